// Round 16
// baseline (2866.466 us; speedup 1.0000x reference)
//
#include <hip/hip_runtime.h>
#include <cmath>

#define NT 256

// ---- problem constants (DEPTH=18, N_ARY=2, H=128, X=128) ----
#define NTOT   262143     // node count (ids 0..262142)
#define NINT   131071     // internal nodes: ids 0 .. 131070

// ws layout (floats) — identical to rounds 6..15 (proven available)
#define WHC_OFF   0                        // [NINT][128] (bias included)
#define WF_OFF    (NINT * 128)             // [NINT][128] (bias included; never overwritten)
#define UFT_OFF   (2 * NINT * 128)         // [256][128] f32
#define UHCT_OFF  (UFT_OFF + 32768)        // [256][128] f32
#define PKWW_OFF  (UHCT_OFF + 32768)       // 24576 slots x 16B bf16 frags
#define PKUF_OFF  (PKWW_OFF + 98304)       // 24576 slots x 16B
#define PKUHC_OFF (PKUF_OFF + 98304)       // 24576 slots x 16B
#define WS_FLOATS (PKUHC_OFF + 98304)
#define WS_BYTES  ((size_t)WS_FLOATS * 4)  // ~135.7 MB

// 6 product blocks p: A-term PA[p], B-term PB[p]
#define PA_PACK 0x120100   // {0,0,1,0,2,1}
#define PB_PACK 0x102010   // {0,1,0,2,0,1}

typedef __attribute__((ext_vector_type(8))) short short8v;
typedef __attribute__((ext_vector_type(4))) float f32x4;

__device__ __forceinline__ float sigmoid_(float v) {
    return 1.0f / (1.0f + expf(-v));
}

// truncation split of fp32 into 3 bf16 terms (exact residuals)
__device__ __forceinline__ void split3(float a, unsigned &t0, unsigned &t1, unsigned &t2) {
    unsigned u0 = __float_as_uint(a) & 0xffff0000u;
    float f0 = __uint_as_float(u0);
    float r1 = a - f0;
    unsigned u1 = __float_as_uint(r1) & 0xffff0000u;
    float f1 = __uint_as_float(u1);
    float r2 = r1 - f1;
    unsigned u2 = __float_as_uint(r2) & 0xffff0000u;
    t0 = u0 >> 16; t1 = u1 >> 16; t2 = u2 >> 16;
}

// =================== weight prep (round-6, proven) ===================
__global__ __launch_bounds__(NT) void prep_pack(
    const float* __restrict__ Ww, const float* __restrict__ Uf,
    const float* __restrict__ Uhc, float* __restrict__ ws)
{
    int t = blockIdx.x * NT + threadIdx.x;
    if (t < 32768) { int k = t >> 7, j = t & 127; ws[UFT_OFF + t] = Uf[j * 256 + k]; return; }
    t -= 32768;
    if (t < 32768) { int k = t >> 7, j = t & 127; ws[UHCT_OFF + t] = Uhc[j * 256 + k]; return; }
    t -= 32768;

    const float* src; int term; uint4* dst; int q;
    if (t < 24576) {                       // PKWW
        q = t;
        int l = q & 63, j = (q >> 6) & 15, s = q >> 10;
        int p = s >> 2, ks = s & 3;
        term = (PB_PACK >> (p * 4)) & 3;
        int kb = ks * 32 + (l >> 4) * 8, col = j * 16 + (l & 15);
        src = Ww + col * 128 + kb;
        dst = (uint4*)(ws + PKWW_OFF);
    } else if (t < 49152) {                // PKUF
        q = t - 24576;
        int l = q & 63, j = (q >> 6) & 7, s = q >> 9;
        int p = s >> 3, ks = s & 7;
        term = (PB_PACK >> (p * 4)) & 3;
        int kb = ks * 32 + (l >> 4) * 8, col = j * 16 + (l & 15);
        src = Uf + col * 256 + kb;
        dst = (uint4*)(ws + PKUF_OFF);
    } else if (t < 73728) {                // PKUHC
        q = t - 49152;
        int l = q & 63, j = (q >> 6) & 7, s = q >> 9;
        int p = s >> 3, ks = s & 7;
        term = (PB_PACK >> (p * 4)) & 3;
        int kb = ks * 32 + (l >> 4) * 8, col = j * 16 + (l & 15);
        src = Uhc + col * 256 + kb;
        dst = (uint4*)(ws + PKUHC_OFF);
    } else return;

    unsigned hv[8];
#pragma unroll
    for (int e = 0; e < 8; ++e) {
        unsigned a, b, c; split3(src[e], a, b, c);
        hv[e] = (term == 0) ? a : (term == 1 ? b : c);
    }
    uint4 o;
    o.x = hv[0] | (hv[1] << 16); o.y = hv[2] | (hv[3] << 16);
    o.z = hv[4] | (hv[5] << 16); o.w = hv[6] | (hv[7] << 16);
    dst[q] = o;
}

// stage helpers: 2048 uint4 (32 KB) per chunk, 512 threads, 4 per thread
#define LOADC(srcbase) { const uint4* s_ = (srcbase); \
    nx0 = s_[tid]; nx1 = s_[tid + 512]; nx2 = s_[tid + 1024]; nx3 = s_[tid + 1536]; }
#define WRITEC(dstbase) { uint4* d_ = (dstbase); \
    d_[tid] = nx0; d_[tid + 512] = nx1; d_[tid + 1024] = nx2; d_[tid + 1536] = nx3; }

// =================== wx_reg3: A-in-regs (STATIC indexing), 64 KB LDS ===================
// 64 nodes/block, 8 waves = (rt 0..3) x (jh 0..1). Lane (li,kg): A row rt*16+li, k=kg*8+ks*32..+7.
__global__ __launch_bounds__(512, 4) void wx_reg3(
    const float* __restrict__ x, const float* __restrict__ ws_all,
    const float* __restrict__ Wb, float* __restrict__ ws, float* __restrict__ h)
{
    __shared__ uint4 sBb[2][2048];            // 64 KB
    const int tid = threadIdx.x;
    const int nbase = blockIdx.x * 64;
    const uint4* pkb = (const uint4*)(ws_all + PKWW_OFF);

    const int lane = tid & 63, wv = tid >> 6;
    const int li = lane & 15, kg = lane >> 4;
    const int rt = wv & 3, jh = wv >> 2;
    const int rowp = rt * 16 + li;

    // ---- stage x tile coalesced into sBb[0], float4-granule XOR swizzle ----
    {
        float4* xs4 = (float4*)&sBb[0][0];
        const float4* xg = (const float4*)x;
        for (int idx = tid; idx < 2048; idx += 512) {
            int row = idx >> 5, q = idx & 31;
            int node = nbase + row; if (node > NTOT - 1) node = NTOT - 1;
            xs4[row * 32 + (q ^ (row & 7))] = xg[(size_t)node * 32 + q];
        }
    }
    __syncthreads();

    // ---- A fragments in registers: 3 split terms x 4 k-steps (static unroll) ----
    short8v fr0[4], fr1[4], fr2[4];
    {
        const float* xls = (const float*)&sBb[0][0] + rowp * 128;
        const int sw = rowp & 7;
#pragma unroll
        for (int ksl = 0; ksl < 4; ++ksl) {
            int g0 = kg * 2 + ksl * 8;
            float4 va = *(const float4*)(xls + ((g0 ^ sw) << 2));
            float4 vb = *(const float4*)(xls + (((g0 + 1) ^ sw) << 2));
            float ev[8] = {va.x, va.y, va.z, va.w, vb.x, vb.y, vb.z, vb.w};
            short8v t0, t1, t2;
#pragma unroll
            for (int e = 0; e < 8; ++e) {
                unsigned b0, b1, b2; split3(ev[e], b0, b1, b2);
                t0[e] = (short)b0; t1[e] = (short)b1; t2[e] = (short)b2;
            }
            fr0[ksl] = t0; fr1[ksl] = t1; fr2[ksl] = t2;
        }
    }
    __syncthreads();   // all frag reads done before sBb[0] reuse

    uint4 nx0, nx1, nx2, nx3;
    LOADC(pkb);
    WRITEC(&sBb[0][0]);
    __syncthreads();

    f32x4 acc[8];
#pragma unroll
    for (int j = 0; j < 8; ++j) acc[j] = (f32x4){0.f, 0.f, 0.f, 0.f};

    int cur = 0;
#pragma unroll 1
    for (int cc = 0; cc < 6; ++cc) {          // product p = cc; 2 chunks per product
        const int spA = (PA_PACK >> (cc * 4)) & 3;
        // register-level 3-way selects (static element indices -> no scratch)
        short8v a0 = (spA == 0) ? fr0[0] : ((spA == 1) ? fr1[0] : fr2[0]);
        short8v a1 = (spA == 0) ? fr0[1] : ((spA == 1) ? fr1[1] : fr2[1]);
        short8v a2 = (spA == 0) ? fr0[2] : ((spA == 1) ? fr1[2] : fr2[2]);
        short8v a3 = (spA == 0) ? fr0[3] : ((spA == 1) ? fr1[3] : fr2[3]);
        {   // chunk c = 2cc : slots ksl 0,1
            int c = 2 * cc;
            if (c < 11) LOADC(pkb + (size_t)(c + 1) * 2048);
            const short8v* sBs = (const short8v*)&sBb[cur][0];
#pragma unroll
            for (int jj = 0; jj < 8; ++jj)
                acc[jj] = __builtin_amdgcn_mfma_f32_16x16x32_bf16(
                    a0, sBs[(jh * 8 + jj) * 64 + lane], acc[jj], 0, 0, 0);
#pragma unroll
            for (int jj = 0; jj < 8; ++jj)
                acc[jj] = __builtin_amdgcn_mfma_f32_16x16x32_bf16(
                    a1, sBs[1024 + (jh * 8 + jj) * 64 + lane], acc[jj], 0, 0, 0);
            if (c < 11) WRITEC(&sBb[cur ^ 1][0]);
            __syncthreads();
            cur ^= 1;
        }
        {   // chunk c = 2cc+1 : slots ksl 2,3
            int c = 2 * cc + 1;
            if (c < 11) LOADC(pkb + (size_t)(c + 1) * 2048);
            const short8v* sBs = (const short8v*)&sBb[cur][0];
#pragma unroll
            for (int jj = 0; jj < 8; ++jj)
                acc[jj] = __builtin_amdgcn_mfma_f32_16x16x32_bf16(
                    a2, sBs[(jh * 8 + jj) * 64 + lane], acc[jj], 0, 0, 0);
#pragma unroll
            for (int jj = 0; jj < 8; ++jj)
                acc[jj] = __builtin_amdgcn_mfma_f32_16x16x32_bf16(
                    a3, sBs[1024 + (jh * 8 + jj) * 64 + lane], acc[jj], 0, 0, 0);
            if (c < 11) WRITEC(&sBb[cur ^ 1][0]);
            __syncthreads();
            cur ^= 1;
        }
    }

    // ---- epilogue: stash acc(+bias) to LDS, then fully-coalesced float4 writes ----
    float* s0 = (float*)&sBb[0][0];           // whc half [64][128]
    float* s1 = (float*)&sBb[1][0];           // wf  half [64][128]
    const int rbase0 = rt * 16 + kg * 4;
    {
        float* dstS = (jh == 0) ? s0 : s1;
        const int cb = jh * 128;
#pragma unroll
        for (int jj = 0; jj < 8; ++jj) {
            int colr = jj * 16 + li;
            float bia = Wb[cb + colr];
#pragma unroll
            for (int r = 0; r < 4; ++r)
                dstS[(rbase0 + r) * 128 + colr] = acc[jj][r] + bia;
        }
    }
    __syncthreads();

    float* whcw = ws + WHC_OFF;
    float* wfw  = ws + WF_OFF;
    for (int idx = tid; idx < 2048; idx += 512) {
        int row = idx >> 5, q = idx & 31;
        int node = nbase + row;
        if (node >= NTOT) continue;
        float4 hc4 = ((const float4*)s0)[idx];
        float4 wf4 = ((const float4*)s1)[idx];
        if (node < NINT) {
            *(float4*)&whcw[(size_t)node * 128 + q * 4] = hc4;
            *(float4*)&wfw [(size_t)node * 128 + q * 4] = wf4;
        } else {
            float4 o;
            float* op = (float*)&o;
            const float* hp = (const float*)&hc4;
            const float* fp = (const float*)&wf4;
#pragma unroll
            for (int j = 0; j < 4; ++j) {
                float f = sigmoid_(fp[j]);
                op[j] = (1.0f - f) * tanhf(hp[j]);
            }
            *(float4*)&h[(size_t)node * 128 + q * 4] = o;
        }
    }
}

// =================== lvl_reg: A-in-registers fused level (big levels 16..12; r13 verbatim) ===================
#define CHOFF(C) ((size_t)((((C) % 6) * 8 + ((C) / 6) * 4)) * 512)

#define CONVF(HLF, FS) { \
    _Pragma("unroll") \
    for (int ksl = 0; ksl < 4; ++ksl) { \
        const float* hp = h + (size_t)(2 * (s0 + rowp) + 1 + (HLF)) * 128 + kg * 8 + ksl * 32; \
        float4 va = *(const float4*)hp; \
        float4 vb = *(const float4*)(hp + 4); \
        if (FS) { \
            int fb = ksl * 32 + kg * 8; \
            float4 f0 = *(const float4*)&f_lds[rowp * 128 + (fb ^ fsw)]; \
            float4 f1 = *(const float4*)&f_lds[rowp * 128 + ((fb + 4) ^ fsw)]; \
            va.x *= f0.x; va.y *= f0.y; va.z *= f0.z; va.w *= f0.w; \
            vb.x *= f1.x; vb.y *= f1.y; vb.z *= f1.z; vb.w *= f1.w; \
        } \
        float ev[8] = {va.x, va.y, va.z, va.w, vb.x, vb.y, vb.z, vb.w}; \
        short8v t0, t1, t2; \
        _Pragma("unroll") \
        for (int e2 = 0; e2 < 8; ++e2) { \
            unsigned b0, b1, b2; split3(ev[e2], b0, b1, b2); \
            t0[e2] = (short)b0; t1[e2] = (short)b1; t2[e2] = (short)b2; \
        } \
        fr0[ksl] = t0; fr1[ksl] = t1; fr2[ksl] = t2; \
    } }

#define MFMAC(BUFP) { \
    const short8v* sBs = (const short8v*)(BUFP); \
    const int spA_ = (PA_PACK >> ((c % 6) * 4)) & 3; \
    _Pragma("unroll") \
    for (int ksl = 0; ksl < 4; ++ksl) { \
        short8v a = (spA_ == 0) ? fr0[ksl] : ((spA_ == 1) ? fr1[ksl] : fr2[ksl]); \
        _Pragma("unroll") \
        for (int jj = 0; jj < 4; ++jj) \
            acc[jj] = __builtin_amdgcn_mfma_f32_16x16x32_bf16(a, sBs[(ksl * 8 + jh * 4 + jj) * 64 + lane], acc[jj], 0, 0, 0); \
    } }

__global__ __launch_bounds__(512, 4) void lvl_reg(
    const float* __restrict__ ws_all, float* __restrict__ h, int start)
{
    __shared__ uint4 sBb[2][2048];            // 64 KB total
    float* f_lds = (float*)&sBb[0][0];        // f[64][128] (XOR-swizzled), lives through P3
    const int tid = threadIdx.x;
    const int s0 = start + blockIdx.x * 64;
    const uint4* ufpk  = (const uint4*)(ws_all + PKUF_OFF);
    const uint4* uhcpk = (const uint4*)(ws_all + PKUHC_OFF);
    const float* wfw   = ws_all + WF_OFF;
    const float* whcw  = ws_all + WHC_OFF;

    const int lane = tid & 63, wv = tid >> 6;
    const int li = lane & 15, kg = lane >> 4;
    const int rt = wv & 3, jh = wv >> 2;
    const int rowp = rt * 16 + li;
    const int fsw = (rowp & 7) << 2;
    const int rbase = rt * 16 + kg * 4;

    short8v fr0[4], fr1[4], fr2[4];
    f32x4 acc[4];
    uint4 nx0, nx1, nx2, nx3;

    // ================= P2 =================
#pragma unroll
    for (int j = 0; j < 4; ++j) acc[j] = (f32x4){0.f, 0.f, 0.f, 0.f};
    CONVF(0, false);
    LOADC(ufpk + CHOFF(0));
    WRITEC(&sBb[0][0]);
    __syncthreads();
    int cur = 0;
#pragma unroll 1
    for (int c = 0; c < 12; ++c) {
        if (c < 11) LOADC(ufpk + CHOFF(c + 1));
        MFMAC(&sBb[cur][0]);
        if (c == 5) CONVF(1, false);
        if (c < 11) WRITEC(&sBb[cur ^ 1][0]);
        __syncthreads();
        cur ^= 1;
    }
#pragma unroll
    for (int jj = 0; jj < 4; ++jj)
#pragma unroll
        for (int r = 0; r < 4; ++r) {
            int col = (jh * 4 + jj) * 16 + li;
            int rowl = rbase + r;
            size_t gn = (size_t)(s0 + rowl);
            float f = sigmoid_(acc[jj][r] + wfw[gn * 128 + col]);
            f_lds[rowl * 128 + (col ^ ((rowl & 7) << 2))] = f;
        }
    __syncthreads();

    // ================= P3 =================
#pragma unroll
    for (int j = 0; j < 4; ++j) acc[j] = (f32x4){0.f, 0.f, 0.f, 0.f};
    CONVF(0, true);
    LOADC(uhcpk + CHOFF(0));
#pragma unroll 1
    for (int c = 0; c < 12; ++c) {
        WRITEC(&sBb[1][0]);
        if (c < 11) LOADC(uhcpk + CHOFF(c + 1));
        __syncthreads();
        MFMAC(&sBb[1][0]);
        if (c == 5) CONVF(1, true);
        __syncthreads();
    }

#pragma unroll
    for (int jj = 0; jj < 4; ++jj)
#pragma unroll
        for (int r = 0; r < 4; ++r) {
            int col = (jh * 4 + jj) * 16 + li;
            int rowl = rbase + r;
            size_t gn = (size_t)(s0 + rowl);
            float f = f_lds[rowl * 128 + (col ^ ((rowl & 7) << 2))];
            float whcv = whcw[gn * 128 + col];
            float c1 = h[(2 * gn + 1) * 128 + col];
            float c2 = h[(2 * gn + 2) * 128 + col];
            float t = tanhf(acc[jj][r] + whcv);
            h[gn * 128 + col] = f * (c1 + c2) + (1.0f - f) * t;
        }
}

// =================== internal level fp32 (round-2, proven) — small levels 11..6 ===================
#define B_NB 32
__global__ __launch_bounds__(NT) void level_kernel(
    const float* __restrict__ ws_all, float* __restrict__ h,
    int start, int size)
{
    __shared__ float sH[B_NB * 256];
    const float* uft  = ws_all + UFT_OFF;
    const float* uhct = ws_all + UHCT_OFF;
    const float* whcw = ws_all + WHC_OFF;
    const float* wfw  = ws_all + WF_OFF;

    const int tid = threadIdx.x;
    const int nbase = blockIdx.x * B_NB;
    const int s0 = start + nbase;
    const int nb = min(B_NB, size - nbase);

    const int jq = tid & 31;  const int j0 = jq << 2;
    const int iq = tid >> 5;  const int i0 = iq << 2;

    {
        const float4* hg = (const float4*)(h + ((size_t)2 * s0 + 1) * 128);
        float4* sH4 = (float4*)sH;
        for (int idx = tid; idx < nb * 64; idx += NT) sH4[idx] = hg[idx];
    }
    __syncthreads();

    const float4* sH4 = (const float4*)sH;

    float fv[4][4];
#pragma unroll
    for (int j = 0; j < 4; ++j)
#pragma unroll
        for (int i = 0; i < 4; ++i) fv[j][i] = 0.f;

    for (int k0 = 0; k0 < 256; k0 += 8) {
        float4 w[8];
#pragma unroll
        for (int u = 0; u < 8; ++u)
            w[u] = *(const float4*)&uft[(size_t)(k0 + u) * 128 + j0];
        float4 a[4][2];
#pragma unroll
        for (int i = 0; i < 4; ++i) {
            a[i][0] = sH4[(i0 + i) * 64 + (k0 >> 2)];
            a[i][1] = sH4[(i0 + i) * 64 + (k0 >> 2) + 1];
        }
#pragma unroll
        for (int u = 0; u < 8; ++u) {
            const float* wp = (const float*)&w[u];
#pragma unroll
            for (int i = 0; i < 4; ++i) {
                float av = ((const float*)&a[i][u >> 2])[u & 3];
#pragma unroll
                for (int j = 0; j < 4; ++j)
                    fv[j][i] = fmaf(wp[j], av, fv[j][i]);
            }
        }
    }
#pragma unroll
    for (int i = 0; i < 4; ++i) {
        float4 wfv = *(const float4*)&wfw[(size_t)(s0 + i0 + i) * 128 + j0];
        const float* wfp = (const float*)&wfv;
#pragma unroll
        for (int j = 0; j < 4; ++j)
            fv[j][i] = sigmoid_(fv[j][i] + wfp[j]);
    }

    __syncthreads();

    float hs[4][4];
#pragma unroll
    for (int i = 0; i < 4; ++i) {
        float4* row = (float4*)&sH[(i0 + i) * 256];
        float4 c0 = row[jq];
        float4 c1 = row[32 + jq];
        hs[0][i] = c0.x + c1.x;
        hs[1][i] = c0.y + c1.y;
        hs[2][i] = c0.z + c1.z;
        hs[3][i] = c0.w + c1.w;
        c0.x *= fv[0][i]; c0.y *= fv[1][i]; c0.z *= fv[2][i]; c0.w *= fv[3][i];
        c1.x *= fv[0][i]; c1.y *= fv[1][i]; c1.z *= fv[2][i]; c1.w *= fv[3][i];
        row[jq] = c0;
        row[32 + jq] = c1;
    }
    __syncthreads();

    float cv[4][4];
#pragma unroll
    for (int j = 0; j < 4; ++j)
#pragma unroll
        for (int i = 0; i < 4; ++i) cv[j][i] = 0.f;

    for (int k0 = 0; k0 < 256; k0 += 8) {
        float4 w[8];
#pragma unroll
        for (int u = 0; u < 8; ++u)
            w[u] = *(const float4*)&uhct[(size_t)(k0 + u) * 128 + j0];
        float4 a[4][2];
#pragma unroll
        for (int i = 0; i < 4; ++i) {
            a[i][0] = sH4[(i0 + i) * 64 + (k0 >> 2)];
            a[i][1] = sH4[(i0 + i) * 64 + (k0 >> 2) + 1];
        }
#pragma unroll
        for (int u = 0; u < 8; ++u) {
            const float* wp = (const float*)&w[u];
#pragma unroll
            for (int i = 0; i < 4; ++i) {
                float av = ((const float*)&a[i][u >> 2])[u & 3];
#pragma unroll
                for (int j = 0; j < 4; ++j)
                    cv[j][i] = fmaf(wp[j], av, cv[j][i]);
            }
        }
    }

#pragma unroll
    for (int i = 0; i < 4; ++i) {
        if (i0 + i < nb) {
            float4 whcv = *(const float4*)&whcw[(size_t)(s0 + i0 + i) * 128 + j0];
            const float* wp = (const float*)&whcv;
            float4 o;
            float* op = (float*)&o;
#pragma unroll
            for (int j = 0; j < 4; ++j) {
                float t = tanhf(cv[j][i] + wp[j]);
                op[j] = fv[j][i] * hs[j][i] + (1.0f - fv[j][i]) * t;
            }
            *(float4*)&h[(size_t)(s0 + i0 + i) * 128 + j0] = o;
        }
    }
}

// =================== tail: levels 5..0 in one block (fp32, proven) ===================
__global__ __launch_bounds__(NT) void tail_kernel(
    const float* __restrict__ ws_all, float* __restrict__ h)
{
    __shared__ __align__(16) float bufA[64 * 128];
    __shared__ __align__(16) float bufB[32 * 128];
    __shared__ __align__(16) float sF[8 * 128];
    const float* uft  = ws_all + UFT_OFF;
    const float* uhct = ws_all + UHCT_OFF;
    const float* whcw = ws_all + WHC_OFF;
    const float* wfw  = ws_all + WF_OFF;

    const int tid = threadIdx.x;
    const int jq = tid & 31;  const int j0 = jq << 2;
    const int iq = tid >> 5;

    {
        const float4* hg = (const float4*)(h + (size_t)63 * 128);
        float4* b4 = (float4*)bufA;
        for (int idx = tid; idx < 64 * 32; idx += NT) b4[idx] = hg[idx];
    }
    __syncthreads();

    float* child = bufA;
    float* cur   = bufB;

    for (int lvl = 5; lvl >= 0; --lvl) {
        const int start = (1 << lvl) - 1;
        const int size  = 1 << lvl;
        for (int pass = 0; pass < size; pass += 8) {
            const int ni = pass + iq;
            const bool act = (ni < size);
            float f[4] = {0.f, 0.f, 0.f, 0.f};
            if (act) {
                const float* hc = child + ni * 256;
                float fv[4] = {0.f, 0.f, 0.f, 0.f};
                for (int k = 0; k < 256; k += 4) {
#pragma unroll
                    for (int u = 0; u < 4; ++u) {
                        float av = hc[k + u];
                        float4 w = *(const float4*)&uft[(size_t)(k + u) * 128 + j0];
                        fv[0] = fmaf(w.x, av, fv[0]);
                        fv[1] = fmaf(w.y, av, fv[1]);
                        fv[2] = fmaf(w.z, av, fv[2]);
                        fv[3] = fmaf(w.w, av, fv[3]);
                    }
                }
                const int gn = start + ni;
                float4 wfv = *(const float4*)&wfw[(size_t)gn * 128 + j0];
                const float* wfp = (const float*)&wfv;
#pragma unroll
                for (int j = 0; j < 4; ++j) {
                    f[j] = sigmoid_(fv[j] + wfp[j]);
                    sF[iq * 128 + j0 + j] = f[j];
                }
            }
            __syncthreads();
            if (act) {
                const float* hc = child + ni * 256;
                const float* fr = sF + iq * 128;
                float cv[4] = {0.f, 0.f, 0.f, 0.f};
                for (int k = 0; k < 256; k += 4) {
#pragma unroll
                    for (int u = 0; u < 4; ++u) {
                        float av = hc[k + u] * fr[(k + u) & 127];
                        float4 w = *(const float4*)&uhct[(size_t)(k + u) * 128 + j0];
                        cv[0] = fmaf(w.x, av, cv[0]);
                        cv[1] = fmaf(w.y, av, cv[1]);
                        cv[2] = fmaf(w.z, av, cv[2]);
                        cv[3] = fmaf(w.w, av, cv[3]);
                    }
                }
                const int gn = start + ni;
                float4 whcv = *(const float4*)&whcw[(size_t)gn * 128 + j0];
                const float* wp = (const float*)&whcv;
                float4 o;
                float* op = (float*)&o;
#pragma unroll
                for (int j = 0; j < 4; ++j) {
                    float hsum = hc[j0 + j] + hc[128 + j0 + j];
                    float t = tanhf(cv[j] + wp[j]);
                    op[j] = f[j] * hsum + (1.0f - f[j]) * t;
                }
                *(float4*)&cur[ni * 128 + j0] = o;
                *(float4*)&h[(size_t)gn * 128 + j0] = o;
            }
            __syncthreads();
        }
        float* t = child; child = cur; cur = t;
    }
}

// =================== fallback path (no workspace; proven) ===================

__global__ __launch_bounds__(NT) void fb_leaf(
    const float* __restrict__ x, const float* __restrict__ Ww,
    const float* __restrict__ Wb, float* __restrict__ h, int start, int size)
{
    __shared__ float sA[32 * 128];
    __shared__ float sW[16 * 260];
    const int tid = threadIdx.x;
    const int nbase = blockIdx.x * 32;
    const int s0 = start + nbase;
    const int nb = min(32, size - nbase);
    const int jq = tid & 31, iq = tid >> 5;
    const int j0 = jq << 2, i0 = iq << 2;
    {
        const float4* xg = (const float4*)(x + (size_t)s0 * 128);
        float4* sA4 = (float4*)sA;
        for (int idx = tid; idx < nb * 32; idx += NT) sA4[idx] = xg[idx];
    }
    float whc[4][4], wf[4][4];
#pragma unroll
    for (int j = 0; j < 4; ++j)
#pragma unroll
        for (int i = 0; i < 4; ++i) { whc[j][i] = 0.f; wf[j][i] = 0.f; }
    for (int k0 = 0; k0 < 128; k0 += 16) {
        __syncthreads();
        const float4* Wg = (const float4*)Ww;
        for (int idx = tid; idx < 256 * 4; idx += NT) {
            int j2 = idx >> 2, kq = idx & 3;
            float4 v = Wg[j2 * 32 + (k0 >> 2) + kq];
            int kb = kq << 2;
            sW[(kb + 0) * 260 + j2] = v.x; sW[(kb + 1) * 260 + j2] = v.y;
            sW[(kb + 2) * 260 + j2] = v.z; sW[(kb + 3) * 260 + j2] = v.w;
        }
        __syncthreads();
#pragma unroll
        for (int kk = 0; kk < 16; kk += 4) {
            float4 a4[4];
#pragma unroll
            for (int i = 0; i < 4; ++i)
                a4[i] = ((const float4*)sA)[(i0 + i) * 32 + ((k0 + kk) >> 2)];
#pragma unroll
            for (int u = 0; u < 4; ++u) {
                int k = kk + u;
                float4 w0 = *((const float4*)&sW[k * 260 + j0]);
                float4 w1 = *((const float4*)&sW[k * 260 + 128 + j0]);
                const float* w0p = (const float*)&w0;
                const float* w1p = (const float*)&w1;
#pragma unroll
                for (int i = 0; i < 4; ++i) {
                    float av = ((const float*)&a4[i])[u];
#pragma unroll
                    for (int j = 0; j < 4; ++j) {
                        whc[j][i] = fmaf(w0p[j], av, whc[j][i]);
                        wf[j][i]  = fmaf(w1p[j], av, wf[j][i]);
                    }
                }
            }
        }
    }
#pragma unroll
    for (int i = 0; i < 4; ++i) {
        if (i0 + i < nb) {
            float4 o; float* op = (float*)&o;
#pragma unroll
            for (int j = 0; j < 4; ++j) {
                float f = sigmoid_(wf[j][i] + Wb[128 + j0 + j]);
                op[j] = (1.0f - f) * tanhf(whc[j][i] + Wb[j0 + j]);
            }
            *(float4*)&h[((size_t)(s0 + i0 + i)) * 128 + j0] = o;
        }
    }
}

__global__ __launch_bounds__(NT) void fb_internal(
    const float* __restrict__ x, const float* __restrict__ Ww,
    const float* __restrict__ Wb, const float* __restrict__ Uf,
    const float* __restrict__ Uhc, float* __restrict__ h, int start, int size)
{
    __shared__ float sA[32 * 256];
    __shared__ float sW[4224];
    const int tid = threadIdx.x;
    const int nbase = blockIdx.x * 32;
    const int s0 = start + nbase;
    const int nb = min(32, size - nbase);
    const int jq = tid & 31, iq = tid >> 5;
    const int j0 = jq << 2, i0 = iq << 2;
    {
        const float4* xg = (const float4*)(x + (size_t)s0 * 128);
        float4* sA4 = (float4*)sA;
        for (int idx = tid; idx < nb * 32; idx += NT) sA4[idx] = xg[idx];
    }
    float whc[4][4], wf[4][4];
#pragma unroll
    for (int j = 0; j < 4; ++j)
#pragma unroll
        for (int i = 0; i < 4; ++i) { whc[j][i] = 0.f; wf[j][i] = 0.f; }
    for (int k0 = 0; k0 < 128; k0 += 16) {
        __syncthreads();
        const float4* Wg = (const float4*)Ww;
        for (int idx = tid; idx < 256 * 4; idx += NT) {
            int j2 = idx >> 2, kq = idx & 3;
            float4 v = Wg[j2 * 32 + (k0 >> 2) + kq];
            int kb = kq << 2;
            sW[(kb + 0) * 260 + j2] = v.x; sW[(kb + 1) * 260 + j2] = v.y;
            sW[(kb + 2) * 260 + j2] = v.z; sW[(kb + 3) * 260 + j2] = v.w;
        }
        __syncthreads();
#pragma unroll
        for (int kk = 0; kk < 16; kk += 4) {
            float4 a4[4];
#pragma unroll
            for (int i = 0; i < 4; ++i)
                a4[i] = ((const float4*)sA)[(i0 + i) * 32 + ((k0 + kk) >> 2)];
#pragma unroll
            for (int u = 0; u < 4; ++u) {
                int k = kk + u;
                float4 w0 = *((const float4*)&sW[k * 260 + j0]);
                float4 w1 = *((const float4*)&sW[k * 260 + 128 + j0]);
                const float* w0p = (const float*)&w0;
                const float* w1p = (const float*)&w1;
#pragma unroll
                for (int i = 0; i < 4; ++i) {
                    float av = ((const float*)&a4[i])[u];
#pragma unroll
                    for (int j = 0; j < 4; ++j) {
                        whc[j][i] = fmaf(w0p[j], av, whc[j][i]);
                        wf[j][i]  = fmaf(w1p[j], av, wf[j][i]);
                    }
                }
            }
        }
    }
#pragma unroll
    for (int j = 0; j < 4; ++j) {
        float bhc = Wb[j0 + j], bf = Wb[128 + j0 + j];
#pragma unroll
        for (int i = 0; i < 4; ++i) { whc[j][i] += bhc; wf[j][i] += bf; }
    }
    __syncthreads();
    {
        const float4* hg = (const float4*)(h + ((size_t)2 * s0 + 1) * 128);
        float4* sA4 = (float4*)sA;
        for (int idx = tid; idx < nb * 64; idx += NT) sA4[idx] = hg[idx];
    }
    float fv[4][4];
#pragma unroll
    for (int j = 0; j < 4; ++j)
#pragma unroll
        for (int i = 0; i < 4; ++i) fv[j][i] = 0.f;
    for (int k0 = 0; k0 < 256; k0 += 32) {
        __syncthreads();
        const float4* Ug = (const float4*)Uf;
        for (int idx = tid; idx < 128 * 8; idx += NT) {
            int j2 = idx >> 3, kq = idx & 7;
            float4 v = Ug[j2 * 64 + (k0 >> 2) + kq];
            int kb = kq << 2;
            sW[(kb + 0) * 132 + j2] = v.x; sW[(kb + 1) * 132 + j2] = v.y;
            sW[(kb + 2) * 132 + j2] = v.z; sW[(kb + 3) * 132 + j2] = v.w;
        }
        __syncthreads();
#pragma unroll
        for (int kk = 0; kk < 32; kk += 4) {
            float4 a4[4];
#pragma unroll
            for (int i = 0; i < 4; ++i)
                a4[i] = ((const float4*)sA)[(i0 + i) * 64 + ((k0 + kk) >> 2)];
#pragma unroll
            for (int u = 0; u < 4; ++u) {
                int k = kk + u;
                float4 w = *((const float4*)&sW[k * 132 + j0]);
                const float* wp = (const float*)&w;
#pragma unroll
                for (int i = 0; i < 4; ++i) {
                    float av = ((const float*)&a4[i])[u];
#pragma unroll
                    for (int j = 0; j < 4; ++j)
                        fv[j][i] = fmaf(wp[j], av, fv[j][i]);
                }
            }
        }
    }
#pragma unroll
    for (int j = 0; j < 4; ++j)
#pragma unroll
        for (int i = 0; i < 4; ++i)
            fv[j][i] = sigmoid_(fv[j][i] + wf[j][i]);
    __syncthreads();
    float hs[4][4];
#pragma unroll
    for (int i = 0; i < 4; ++i) {
        float4* row = (float4*)&sA[(i0 + i) * 256];
        float4 c0 = row[jq], c1 = row[32 + jq];
        hs[0][i] = c0.x + c1.x; hs[1][i] = c0.y + c1.y;
        hs[2][i] = c0.z + c1.z; hs[3][i] = c0.w + c1.w;
        c0.x *= fv[0][i]; c0.y *= fv[1][i]; c0.z *= fv[2][i]; c0.w *= fv[3][i];
        c1.x *= fv[0][i]; c1.y *= fv[1][i]; c1.z *= fv[2][i]; c1.w *= fv[3][i];
        row[jq] = c0; row[32 + jq] = c1;
    }
    float cv[4][4];
#pragma unroll
    for (int j = 0; j < 4; ++j)
#pragma unroll
        for (int i = 0; i < 4; ++i) cv[j][i] = 0.f;
    for (int k0 = 0; k0 < 256; k0 += 32) {
        __syncthreads();
        const float4* Ug = (const float4*)Uhc;
        for (int idx = tid; idx < 128 * 8; idx += NT) {
            int j2 = idx >> 3, kq = idx & 7;
            float4 v = Ug[j2 * 64 + (k0 >> 2) + kq];
            int kb = kq << 2;
            sW[(kb + 0) * 132 + j2] = v.x; sW[(kb + 1) * 132 + j2] = v.y;
            sW[(kb + 2) * 132 + j2] = v.z; sW[(kb + 3) * 132 + j2] = v.w;
        }
        __syncthreads();
#pragma unroll
        for (int kk = 0; kk < 32; kk += 4) {
            float4 a4[4];
#pragma unroll
            for (int i = 0; i < 4; ++i)
                a4[i] = ((const float4*)sA)[(i0 + i) * 64 + ((k0 + kk) >> 2)];
#pragma unroll
            for (int u = 0; u < 4; ++u) {
                int k = kk + u;
                float4 w = *((const float4*)&sW[k * 132 + j0]);
                const float* wp = (const float*)&w;
#pragma unroll
                for (int i = 0; i < 4; ++i) {
                    float av = ((const float*)&a4[i])[u];
#pragma unroll
                    for (int j = 0; j < 4; ++j)
                        cv[j][i] = fmaf(wp[j], av, cv[j][i]);
                }
            }
        }
    }
#pragma unroll
    for (int i = 0; i < 4; ++i) {
        if (i0 + i < nb) {
            float4 o; float* op = (float*)&o;
#pragma unroll
            for (int j = 0; j < 4; ++j) {
                float t = tanhf(cv[j][i] + whc[j][i]);
                op[j] = fv[j][i] * hs[j][i] + (1.0f - fv[j][i]) * t;
            }
            *(float4*)&h[((size_t)(s0 + i0 + i)) * 128 + j0] = o;
        }
    }
}

// =================== launcher ===================

extern "C" void kernel_launch(void* const* d_in, const int* in_sizes, int n_in,
                              void* d_out, int out_size, void* d_ws, size_t ws_size,
                              hipStream_t stream)
{
    (void)in_sizes; (void)n_in; (void)out_size;
    const float* x   = (const float*)d_in[0];
    const float* Ww  = (const float*)d_in[1];
    const float* Wb  = (const float*)d_in[2];
    const float* Uf  = (const float*)d_in[3];
    const float* Uhc = (const float*)d_in[4];
    float* h = (float*)d_out;
    const int depth = 18;

    if (ws_size >= WS_BYTES) {
        float* ws = (float*)d_ws;
        prep_pack<<<544, NT, 0, stream>>>(Ww, Uf, Uhc, ws);
        wx_reg3<<<(NTOT + 63) / 64, 512, 0, stream>>>(x, ws, Wb, ws, h);
        for (int lvl = 16; lvl >= 12; --lvl)                     // big levels: A-in-reg MFMA
            lvl_reg<<<1 << (lvl - 6), 512, 0, stream>>>(ws, h, (1 << lvl) - 1);
        for (int lvl = 11; lvl >= 6; --lvl) {                    // small levels: fp32, low latency
            int start = (1 << lvl) - 1;
            int size  = 1 << lvl;
            level_kernel<<<(size + B_NB - 1) / B_NB, NT, 0, stream>>>(ws, h, start, size);
        }
        tail_kernel<<<1, NT, 0, stream>>>(ws, h);
    } else {
        {
            int lvl = depth - 1;
            int start = (1 << lvl) - 1, size = 1 << lvl;
            fb_leaf<<<(size + 31) / 32, NT, 0, stream>>>(x, Ww, Wb, h, start, size);
        }
        for (int lvl = depth - 2; lvl >= 0; --lvl) {
            int start = (1 << lvl) - 1, size = 1 << lvl;
            fb_internal<<<(size + 31) / 32, NT, 0, stream>>>(x, Ww, Wb, Uf, Uhc, h, start, size);
        }
    }
}

// Round 17
// 797.802 us; speedup vs baseline: 3.5930x; 3.5930x over previous
//
#include <hip/hip_runtime.h>
#include <cmath>

#define NT 256

// ---- problem constants (DEPTH=18, N_ARY=2, H=128, X=128) ----
#define NTOT   262143     // node count (ids 0..262142)
#define NINT   131071     // internal nodes: ids 0 .. 131070

// ws layout (floats) — identical to rounds 6..16 (proven available)
#define WHC_OFF   0                        // [NINT][128] (bias included)
#define WF_OFF    (NINT * 128)             // [NINT][128] (bias included; never overwritten)
#define UFT_OFF   (2 * NINT * 128)         // [256][128] f32
#define UHCT_OFF  (UFT_OFF + 32768)        // [256][128] f32
#define PKWW_OFF  (UHCT_OFF + 32768)       // 24576 slots x 16B bf16 frags
#define PKUF_OFF  (PKWW_OFF + 98304)       // 24576 slots x 16B
#define PKUHC_OFF (PKUF_OFF + 98304)       // 24576 slots x 16B
#define WS_FLOATS (PKUHC_OFF + 98304)
#define WS_BYTES  ((size_t)WS_FLOATS * 4)  // ~135.7 MB

// 6 product blocks p: A-term PA[p], B-term PB[p]
#define PA_PACK 0x120100   // {0,0,1,0,2,1}
#define PB_PACK 0x102010   // {0,1,0,2,0,1}

typedef __attribute__((ext_vector_type(8))) short short8v;
typedef __attribute__((ext_vector_type(4))) float f32x4;

__device__ __forceinline__ float sigmoid_(float v) {
    return 1.0f / (1.0f + expf(-v));
}

// truncation split of fp32 into 3 bf16 terms (exact residuals)
__device__ __forceinline__ void split3(float a, unsigned &t0, unsigned &t1, unsigned &t2) {
    unsigned u0 = __float_as_uint(a) & 0xffff0000u;
    float f0 = __uint_as_float(u0);
    float r1 = a - f0;
    unsigned u1 = __float_as_uint(r1) & 0xffff0000u;
    float f1 = __uint_as_float(u1);
    float r2 = r1 - f1;
    unsigned u2 = __float_as_uint(r2) & 0xffff0000u;
    t0 = u0 >> 16; t1 = u1 >> 16; t2 = u2 >> 16;
}

// =================== weight prep (round-6, proven) ===================
__global__ __launch_bounds__(NT) void prep_pack(
    const float* __restrict__ Ww, const float* __restrict__ Uf,
    const float* __restrict__ Uhc, float* __restrict__ ws)
{
    int t = blockIdx.x * NT + threadIdx.x;
    if (t < 32768) { int k = t >> 7, j = t & 127; ws[UFT_OFF + t] = Uf[j * 256 + k]; return; }
    t -= 32768;
    if (t < 32768) { int k = t >> 7, j = t & 127; ws[UHCT_OFF + t] = Uhc[j * 256 + k]; return; }
    t -= 32768;

    const float* src; int term; uint4* dst; int q;
    if (t < 24576) {                       // PKWW
        q = t;
        int l = q & 63, j = (q >> 6) & 15, s = q >> 10;
        int p = s >> 2, ks = s & 3;
        term = (PB_PACK >> (p * 4)) & 3;
        int kb = ks * 32 + (l >> 4) * 8, col = j * 16 + (l & 15);
        src = Ww + col * 128 + kb;
        dst = (uint4*)(ws + PKWW_OFF);
    } else if (t < 49152) {                // PKUF
        q = t - 24576;
        int l = q & 63, j = (q >> 6) & 7, s = q >> 9;
        int p = s >> 3, ks = s & 7;
        term = (PB_PACK >> (p * 4)) & 3;
        int kb = ks * 32 + (l >> 4) * 8, col = j * 16 + (l & 15);
        src = Uf + col * 256 + kb;
        dst = (uint4*)(ws + PKUF_OFF);
    } else if (t < 73728) {                // PKUHC
        q = t - 49152;
        int l = q & 63, j = (q >> 6) & 7, s = q >> 9;
        int p = s >> 3, ks = s & 7;
        term = (PB_PACK >> (p * 4)) & 3;
        int kb = ks * 32 + (l >> 4) * 8, col = j * 16 + (l & 15);
        src = Uhc + col * 256 + kb;
        dst = (uint4*)(ws + PKUHC_OFF);
    } else return;

    unsigned hv[8];
#pragma unroll
    for (int e = 0; e < 8; ++e) {
        unsigned a, b, c; split3(src[e], a, b, c);
        hv[e] = (term == 0) ? a : (term == 1 ? b : c);
    }
    uint4 o;
    o.x = hv[0] | (hv[1] << 16); o.y = hv[2] | (hv[3] << 16);
    o.z = hv[4] | (hv[5] << 16); o.w = hv[6] | (hv[7] << 16);
    dst[q] = o;
}

// stage helpers: 2048 uint4 (32 KB) per chunk, 512 threads, 4 per thread
#define LOADC(srcbase) { const uint4* s_ = (srcbase); \
    nx0 = s_[tid]; nx1 = s_[tid + 512]; nx2 = s_[tid + 1024]; nx3 = s_[tid + 1536]; }
#define WRITEC(dstbase) { uint4* d_ = (dstbase); \
    d_[tid] = nx0; d_[tid + 512] = nx1; d_[tid + 1024] = nx2; d_[tid + 1536] = nx3; }

// =================== wx: 128 nodes/block, 8 waves, dbuf B chunks (r10, proven) ===================
__global__ __launch_bounds__(512) void wx_mfma4(
    const float* __restrict__ x, const float* __restrict__ ws_all,
    const float* __restrict__ Wb, float* __restrict__ ws, float* __restrict__ h)
{
    __shared__ short As[128 * 384];           // 96 KB A-pack
    __shared__ uint4 sBb[2][2048];            // 2 x 32 KB B chunk buffers
    char* Asb = (char*)As;
    const int tid = threadIdx.x;
    const int nbase = blockIdx.x * 128;
    const uint4* pkb = (const uint4*)(ws_all + PKWW_OFF);

    uint4 nx0, nx1, nx2, nx3;
    LOADC(pkb);                               // chunk 0 -> regs (lands during conversion)

    // ---- convert x tile -> 3-term bf16 A-pack ----
    for (int i = 0; i < 8; ++i) {
        int idx = i * 512 + tid;
        int m = idx >> 5, g = idx & 31;
        int node = nbase + m; if (node > NTOT - 1) node = NTOT - 1;
        float4 v = *(const float4*)(x + (size_t)node * 128 + g * 4);
        unsigned a0[4], a1[4], a2[4];
        split3(v.x, a0[0], a1[0], a2[0]); split3(v.y, a0[1], a1[1], a2[1]);
        split3(v.z, a0[2], a1[2], a2[2]); split3(v.w, a0[3], a1[3], a2[3]);
        int ks = g >> 3, kg = (g >> 1) & 3, hw = (g & 1) * 8;
        int kss = ks ^ ((m >> 2) & 3), kgs = kg ^ (m & 3);
        char* base = Asb + m * 768 + kgs * 16 + hw;
        *(uint2*)(base + ((0 * 4 + kss) << 6)) = make_uint2(a0[0] | (a0[1] << 16), a0[2] | (a0[3] << 16));
        *(uint2*)(base + ((1 * 4 + kss) << 6)) = make_uint2(a1[0] | (a1[1] << 16), a1[2] | (a1[3] << 16));
        *(uint2*)(base + ((2 * 4 + kss) << 6)) = make_uint2(a2[0] | (a2[1] << 16), a2[2] | (a2[3] << 16));
    }
    WRITEC(&sBb[0][0]);
    __syncthreads();

    const int lane = tid & 63, wv = tid >> 6;
    const int li = lane & 15, kg = lane >> 4;
    const int mf = wv * 16 + li;
    const int mswz = (mf >> 2) & 3;
    const char* arbase = Asb + mf * 768 + ((kg ^ (mf & 3)) << 4);

    f32x4 acc[16];
#pragma unroll
    for (int j = 0; j < 16; ++j) acc[j] = (f32x4){0.f, 0.f, 0.f, 0.f};

    int cur = 0;
#pragma unroll 1
    for (int c = 0; c < 12; ++c) {
        if (c < 11) LOADC(pkb + (size_t)(c + 1) * 2048);
        const int p = c >> 1, hh = c & 1;
        const int spA = (PA_PACK >> (p * 4)) & 3;
        const short8v* sBs = (const short8v*)&sBb[cur][0];
#pragma unroll
        for (int ks2 = 0; ks2 < 2; ++ks2) {
            int ks = hh * 2 + ks2;
            short8v a = *(const short8v*)(arbase + ((spA * 4 + (ks ^ mswz)) << 6));
#pragma unroll
            for (int j = 0; j < 16; ++j)
                acc[j] = __builtin_amdgcn_mfma_f32_16x16x32_bf16(a, sBs[(ks2 * 16 + j) * 64 + lane], acc[j], 0, 0, 0);
        }
        if (c < 11) WRITEC(&sBb[cur ^ 1][0]);
        __syncthreads();
        cur ^= 1;
    }

    // ---- epilogue ----
    float* whcw = ws + WHC_OFF;
    float* wfw  = ws + WF_OFF;
    const int rbase = wv * 16 + kg * 4;
#pragma unroll
    for (int r = 0; r < 4; ++r) {
        int node = nbase + rbase + r;
        if (node >= NTOT) continue;
        if (node < NINT) {
#pragma unroll
            for (int j = 0; j < 16; ++j) {
                int col = j * 16 + li;
                float v = acc[j][r] + Wb[col];
                if (col < 128) whcw[(size_t)node * 128 + col] = v;
                else           wfw [(size_t)node * 128 + col - 128] = v;
            }
        } else {
#pragma unroll
            for (int j = 0; j < 8; ++j) {
                int col = j * 16 + li;
                float hc = acc[j][r] + Wb[col];
                float wf = acc[j + 8][r] + Wb[col + 128];
                float f = sigmoid_(wf);
                h[(size_t)node * 128 + col] = (1.0f - f) * tanhf(hc);
            }
        }
    }
}

// =================== lvl_reg: A-in-registers fused level (big levels 16..12; r13 verbatim) ===================
#define CHOFF(C) ((size_t)((((C) % 6) * 8 + ((C) / 6) * 4)) * 512)

#define CONVF(HLF, FS) { \
    _Pragma("unroll") \
    for (int ksl = 0; ksl < 4; ++ksl) { \
        const float* hp = h + (size_t)(2 * (s0 + rowp) + 1 + (HLF)) * 128 + kg * 8 + ksl * 32; \
        float4 va = *(const float4*)hp; \
        float4 vb = *(const float4*)(hp + 4); \
        if (FS) { \
            int fb = ksl * 32 + kg * 8; \
            float4 f0 = *(const float4*)&f_lds[rowp * 128 + (fb ^ fsw)]; \
            float4 f1 = *(const float4*)&f_lds[rowp * 128 + ((fb + 4) ^ fsw)]; \
            va.x *= f0.x; va.y *= f0.y; va.z *= f0.z; va.w *= f0.w; \
            vb.x *= f1.x; vb.y *= f1.y; vb.z *= f1.z; vb.w *= f1.w; \
        } \
        float ev[8] = {va.x, va.y, va.z, va.w, vb.x, vb.y, vb.z, vb.w}; \
        short8v t0, t1, t2; \
        _Pragma("unroll") \
        for (int e2 = 0; e2 < 8; ++e2) { \
            unsigned b0, b1, b2; split3(ev[e2], b0, b1, b2); \
            t0[e2] = (short)b0; t1[e2] = (short)b1; t2[e2] = (short)b2; \
        } \
        fr0[ksl] = t0; fr1[ksl] = t1; fr2[ksl] = t2; \
    } }

#define MFMAC(BUFP) { \
    const short8v* sBs = (const short8v*)(BUFP); \
    const int spA_ = (PA_PACK >> ((c % 6) * 4)) & 3; \
    _Pragma("unroll") \
    for (int ksl = 0; ksl < 4; ++ksl) { \
        short8v a = (spA_ == 0) ? fr0[ksl] : ((spA_ == 1) ? fr1[ksl] : fr2[ksl]); \
        _Pragma("unroll") \
        for (int jj = 0; jj < 4; ++jj) \
            acc[jj] = __builtin_amdgcn_mfma_f32_16x16x32_bf16(a, sBs[(ksl * 8 + jh * 4 + jj) * 64 + lane], acc[jj], 0, 0, 0); \
    } }

__global__ __launch_bounds__(512, 4) void lvl_reg(
    const float* __restrict__ ws_all, float* __restrict__ h, int start)
{
    __shared__ uint4 sBb[2][2048];            // 64 KB total
    float* f_lds = (float*)&sBb[0][0];        // f[64][128] (XOR-swizzled), lives through P3
    const int tid = threadIdx.x;
    const int s0 = start + blockIdx.x * 64;
    const uint4* ufpk  = (const uint4*)(ws_all + PKUF_OFF);
    const uint4* uhcpk = (const uint4*)(ws_all + PKUHC_OFF);
    const float* wfw   = ws_all + WF_OFF;
    const float* whcw  = ws_all + WHC_OFF;

    const int lane = tid & 63, wv = tid >> 6;
    const int li = lane & 15, kg = lane >> 4;
    const int rt = wv & 3, jh = wv >> 2;
    const int rowp = rt * 16 + li;
    const int fsw = (rowp & 7) << 2;
    const int rbase = rt * 16 + kg * 4;

    short8v fr0[4], fr1[4], fr2[4];
    f32x4 acc[4];
    uint4 nx0, nx1, nx2, nx3;

    // ================= P2 =================
#pragma unroll
    for (int j = 0; j < 4; ++j) acc[j] = (f32x4){0.f, 0.f, 0.f, 0.f};
    CONVF(0, false);
    LOADC(ufpk + CHOFF(0));
    WRITEC(&sBb[0][0]);
    __syncthreads();
    int cur = 0;
#pragma unroll 1
    for (int c = 0; c < 12; ++c) {
        if (c < 11) LOADC(ufpk + CHOFF(c + 1));
        MFMAC(&sBb[cur][0]);
        if (c == 5) CONVF(1, false);
        if (c < 11) WRITEC(&sBb[cur ^ 1][0]);
        __syncthreads();
        cur ^= 1;
    }
#pragma unroll
    for (int jj = 0; jj < 4; ++jj)
#pragma unroll
        for (int r = 0; r < 4; ++r) {
            int col = (jh * 4 + jj) * 16 + li;
            int rowl = rbase + r;
            size_t gn = (size_t)(s0 + rowl);
            float f = sigmoid_(acc[jj][r] + wfw[gn * 128 + col]);
            f_lds[rowl * 128 + (col ^ ((rowl & 7) << 2))] = f;
        }
    __syncthreads();

    // ================= P3 =================
#pragma unroll
    for (int j = 0; j < 4; ++j) acc[j] = (f32x4){0.f, 0.f, 0.f, 0.f};
    CONVF(0, true);
    LOADC(uhcpk + CHOFF(0));
#pragma unroll 1
    for (int c = 0; c < 12; ++c) {
        WRITEC(&sBb[1][0]);                   // buf1 only; f_lds (buf0) stays live
        if (c < 11) LOADC(uhcpk + CHOFF(c + 1));
        __syncthreads();
        MFMAC(&sBb[1][0]);
        if (c == 5) CONVF(1, true);
        __syncthreads();
    }

#pragma unroll
    for (int jj = 0; jj < 4; ++jj)
#pragma unroll
        for (int r = 0; r < 4; ++r) {
            int col = (jh * 4 + jj) * 16 + li;
            int rowl = rbase + r;
            size_t gn = (size_t)(s0 + rowl);
            float f = f_lds[rowl * 128 + (col ^ ((rowl & 7) << 2))];
            float whcv = whcw[gn * 128 + col];
            float c1 = h[(2 * gn + 1) * 128 + col];
            float c2 = h[(2 * gn + 2) * 128 + col];
            float t = tanhf(acc[jj][r] + whcv);
            h[gn * 128 + col] = f * (c1 + c2) + (1.0f - f) * t;
        }
}

// =================== internal level fp32 (round-2, proven) — small levels 11..6 ===================
#define B_NB 32
__global__ __launch_bounds__(NT) void level_kernel(
    const float* __restrict__ ws_all, float* __restrict__ h,
    int start, int size)
{
    __shared__ float sH[B_NB * 256];
    const float* uft  = ws_all + UFT_OFF;
    const float* uhct = ws_all + UHCT_OFF;
    const float* whcw = ws_all + WHC_OFF;
    const float* wfw  = ws_all + WF_OFF;

    const int tid = threadIdx.x;
    const int nbase = blockIdx.x * B_NB;
    const int s0 = start + nbase;
    const int nb = min(B_NB, size - nbase);

    const int jq = tid & 31;  const int j0 = jq << 2;
    const int iq = tid >> 5;  const int i0 = iq << 2;

    {
        const float4* hg = (const float4*)(h + ((size_t)2 * s0 + 1) * 128);
        float4* sH4 = (float4*)sH;
        for (int idx = tid; idx < nb * 64; idx += NT) sH4[idx] = hg[idx];
    }
    __syncthreads();

    const float4* sH4 = (const float4*)sH;

    float fv[4][4];
#pragma unroll
    for (int j = 0; j < 4; ++j)
#pragma unroll
        for (int i = 0; i < 4; ++i) fv[j][i] = 0.f;

    for (int k0 = 0; k0 < 256; k0 += 8) {
        float4 w[8];
#pragma unroll
        for (int u = 0; u < 8; ++u)
            w[u] = *(const float4*)&uft[(size_t)(k0 + u) * 128 + j0];
        float4 a[4][2];
#pragma unroll
        for (int i = 0; i < 4; ++i) {
            a[i][0] = sH4[(i0 + i) * 64 + (k0 >> 2)];
            a[i][1] = sH4[(i0 + i) * 64 + (k0 >> 2) + 1];
        }
#pragma unroll
        for (int u = 0; u < 8; ++u) {
            const float* wp = (const float*)&w[u];
#pragma unroll
            for (int i = 0; i < 4; ++i) {
                float av = ((const float*)&a[i][u >> 2])[u & 3];
#pragma unroll
                for (int j = 0; j < 4; ++j)
                    fv[j][i] = fmaf(wp[j], av, fv[j][i]);
            }
        }
    }
#pragma unroll
    for (int i = 0; i < 4; ++i) {
        float4 wfv = *(const float4*)&wfw[(size_t)(s0 + i0 + i) * 128 + j0];
        const float* wfp = (const float*)&wfv;
#pragma unroll
        for (int j = 0; j < 4; ++j)
            fv[j][i] = sigmoid_(fv[j][i] + wfp[j]);
    }

    __syncthreads();

    float hs[4][4];
#pragma unroll
    for (int i = 0; i < 4; ++i) {
        float4* row = (float4*)&sH[(i0 + i) * 256];
        float4 c0 = row[jq];
        float4 c1 = row[32 + jq];
        hs[0][i] = c0.x + c1.x;
        hs[1][i] = c0.y + c1.y;
        hs[2][i] = c0.z + c1.z;
        hs[3][i] = c0.w + c1.w;
        c0.x *= fv[0][i]; c0.y *= fv[1][i]; c0.z *= fv[2][i]; c0.w *= fv[3][i];
        c1.x *= fv[0][i]; c1.y *= fv[1][i]; c1.z *= fv[2][i]; c1.w *= fv[3][i];
        row[jq] = c0;
        row[32 + jq] = c1;
    }
    __syncthreads();

    float cv[4][4];
#pragma unroll
    for (int j = 0; j < 4; ++j)
#pragma unroll
        for (int i = 0; i < 4; ++i) cv[j][i] = 0.f;

    for (int k0 = 0; k0 < 256; k0 += 8) {
        float4 w[8];
#pragma unroll
        for (int u = 0; u < 8; ++u)
            w[u] = *(const float4*)&uhct[(size_t)(k0 + u) * 128 + j0];
        float4 a[4][2];
#pragma unroll
        for (int i = 0; i < 4; ++i) {
            a[i][0] = sH4[(i0 + i) * 64 + (k0 >> 2)];
            a[i][1] = sH4[(i0 + i) * 64 + (k0 >> 2) + 1];
        }
#pragma unroll
        for (int u = 0; u < 8; ++u) {
            const float* wp = (const float*)&w[u];
#pragma unroll
            for (int i = 0; i < 4; ++i) {
                float av = ((const float*)&a[i][u >> 2])[u & 3];
#pragma unroll
                for (int j = 0; j < 4; ++j)
                    cv[j][i] = fmaf(wp[j], av, cv[j][i]);
            }
        }
    }

#pragma unroll
    for (int i = 0; i < 4; ++i) {
        if (i0 + i < nb) {
            float4 whcv = *(const float4*)&whcw[(size_t)(s0 + i0 + i) * 128 + j0];
            const float* wp = (const float*)&whcv;
            float4 o;
            float* op = (float*)&o;
#pragma unroll
            for (int j = 0; j < 4; ++j) {
                float t = tanhf(cv[j][i] + wp[j]);
                op[j] = fv[j][i] * hs[j][i] + (1.0f - fv[j][i]) * t;
            }
            *(float4*)&h[(size_t)(s0 + i0 + i) * 128 + j0] = o;
        }
    }
}

// =================== tail: levels 5..0 in one block (fp32, proven) ===================
__global__ __launch_bounds__(NT) void tail_kernel(
    const float* __restrict__ ws_all, float* __restrict__ h)
{
    __shared__ __align__(16) float bufA[64 * 128];
    __shared__ __align__(16) float bufB[32 * 128];
    __shared__ __align__(16) float sF[8 * 128];
    const float* uft  = ws_all + UFT_OFF;
    const float* uhct = ws_all + UHCT_OFF;
    const float* whcw = ws_all + WHC_OFF;
    const float* wfw  = ws_all + WF_OFF;

    const int tid = threadIdx.x;
    const int jq = tid & 31;  const int j0 = jq << 2;
    const int iq = tid >> 5;

    {
        const float4* hg = (const float4*)(h + (size_t)63 * 128);
        float4* b4 = (float4*)bufA;
        for (int idx = tid; idx < 64 * 32; idx += NT) b4[idx] = hg[idx];
    }
    __syncthreads();

    float* child = bufA;
    float* cur   = bufB;

    for (int lvl = 5; lvl >= 0; --lvl) {
        const int start = (1 << lvl) - 1;
        const int size  = 1 << lvl;
        for (int pass = 0; pass < size; pass += 8) {
            const int ni = pass + iq;
            const bool act = (ni < size);
            float f[4] = {0.f, 0.f, 0.f, 0.f};
            if (act) {
                const float* hc = child + ni * 256;
                float fv[4] = {0.f, 0.f, 0.f, 0.f};
                for (int k = 0; k < 256; k += 4) {
#pragma unroll
                    for (int u = 0; u < 4; ++u) {
                        float av = hc[k + u];
                        float4 w = *(const float4*)&uft[(size_t)(k + u) * 128 + j0];
                        fv[0] = fmaf(w.x, av, fv[0]);
                        fv[1] = fmaf(w.y, av, fv[1]);
                        fv[2] = fmaf(w.z, av, fv[2]);
                        fv[3] = fmaf(w.w, av, fv[3]);
                    }
                }
                const int gn = start + ni;
                float4 wfv = *(const float4*)&wfw[(size_t)gn * 128 + j0];
                const float* wfp = (const float*)&wfv;
#pragma unroll
                for (int j = 0; j < 4; ++j) {
                    f[j] = sigmoid_(fv[j] + wfp[j]);
                    sF[iq * 128 + j0 + j] = f[j];
                }
            }
            __syncthreads();
            if (act) {
                const float* hc = child + ni * 256;
                const float* fr = sF + iq * 128;
                float cv[4] = {0.f, 0.f, 0.f, 0.f};
                for (int k = 0; k < 256; k += 4) {
#pragma unroll
                    for (int u = 0; u < 4; ++u) {
                        float av = hc[k + u] * fr[(k + u) & 127];
                        float4 w = *(const float4*)&uhct[(size_t)(k + u) * 128 + j0];
                        cv[0] = fmaf(w.x, av, cv[0]);
                        cv[1] = fmaf(w.y, av, cv[1]);
                        cv[2] = fmaf(w.z, av, cv[2]);
                        cv[3] = fmaf(w.w, av, cv[3]);
                    }
                }
                const int gn = start + ni;
                float4 whcv = *(const float4*)&whcw[(size_t)gn * 128 + j0];
                const float* wp = (const float*)&whcv;
                float4 o;
                float* op = (float*)&o;
#pragma unroll
                for (int j = 0; j < 4; ++j) {
                    float hsum = hc[j0 + j] + hc[128 + j0 + j];
                    float t = tanhf(cv[j] + wp[j]);
                    op[j] = f[j] * hsum + (1.0f - f[j]) * t;
                }
                *(float4*)&cur[ni * 128 + j0] = o;
                *(float4*)&h[(size_t)gn * 128 + j0] = o;
            }
            __syncthreads();
        }
        float* t = child; child = cur; cur = t;
    }
}

// =================== fallback path (no workspace; proven) ===================

__global__ __launch_bounds__(NT) void fb_leaf(
    const float* __restrict__ x, const float* __restrict__ Ww,
    const float* __restrict__ Wb, float* __restrict__ h, int start, int size)
{
    __shared__ float sA[32 * 128];
    __shared__ float sW[16 * 260];
    const int tid = threadIdx.x;
    const int nbase = blockIdx.x * 32;
    const int s0 = start + nbase;
    const int nb = min(32, size - nbase);
    const int jq = tid & 31, iq = tid >> 5;
    const int j0 = jq << 2, i0 = iq << 2;
    {
        const float4* xg = (const float4*)(x + (size_t)s0 * 128);
        float4* sA4 = (float4*)sA;
        for (int idx = tid; idx < nb * 32; idx += NT) sA4[idx] = xg[idx];
    }
    float whc[4][4], wf[4][4];
#pragma unroll
    for (int j = 0; j < 4; ++j)
#pragma unroll
        for (int i = 0; i < 4; ++i) { whc[j][i] = 0.f; wf[j][i] = 0.f; }
    for (int k0 = 0; k0 < 128; k0 += 16) {
        __syncthreads();
        const float4* Wg = (const float4*)Ww;
        for (int idx = tid; idx < 256 * 4; idx += NT) {
            int j2 = idx >> 2, kq = idx & 3;
            float4 v = Wg[j2 * 32 + (k0 >> 2) + kq];
            int kb = kq << 2;
            sW[(kb + 0) * 260 + j2] = v.x; sW[(kb + 1) * 260 + j2] = v.y;
            sW[(kb + 2) * 260 + j2] = v.z; sW[(kb + 3) * 260 + j2] = v.w;
        }
        __syncthreads();
#pragma unroll
        for (int kk = 0; kk < 16; kk += 4) {
            float4 a4[4];
#pragma unroll
            for (int i = 0; i < 4; ++i)
                a4[i] = ((const float4*)sA)[(i0 + i) * 32 + ((k0 + kk) >> 2)];
#pragma unroll
            for (int u = 0; u < 4; ++u) {
                int k = kk + u;
                float4 w0 = *((const float4*)&sW[k * 260 + j0]);
                float4 w1 = *((const float4*)&sW[k * 260 + 128 + j0]);
                const float* w0p = (const float*)&w0;
                const float* w1p = (const float*)&w1;
#pragma unroll
                for (int i = 0; i < 4; ++i) {
                    float av = ((const float*)&a4[i])[u];
#pragma unroll
                    for (int j = 0; j < 4; ++j) {
                        whc[j][i] = fmaf(w0p[j], av, whc[j][i]);
                        wf[j][i]  = fmaf(w1p[j], av, wf[j][i]);
                    }
                }
            }
        }
    }
#pragma unroll
    for (int i = 0; i < 4; ++i) {
        if (i0 + i < nb) {
            float4 o; float* op = (float*)&o;
#pragma unroll
            for (int j = 0; j < 4; ++j) {
                float f = sigmoid_(wf[j][i] + Wb[128 + j0 + j]);
                op[j] = (1.0f - f) * tanhf(whc[j][i] + Wb[j0 + j]);
            }
            *(float4*)&h[((size_t)(s0 + i0 + i)) * 128 + j0] = o;
        }
    }
}

__global__ __launch_bounds__(NT) void fb_internal(
    const float* __restrict__ x, const float* __restrict__ Ww,
    const float* __restrict__ Wb, const float* __restrict__ Uf,
    const float* __restrict__ Uhc, float* __restrict__ h, int start, int size)
{
    __shared__ float sA[32 * 256];
    __shared__ float sW[4224];
    const int tid = threadIdx.x;
    const int nbase = blockIdx.x * 32;
    const int s0 = start + nbase;
    const int nb = min(32, size - nbase);
    const int jq = tid & 31, iq = tid >> 5;
    const int j0 = jq << 2, i0 = iq << 2;
    {
        const float4* xg = (const float4*)(x + (size_t)s0 * 128);
        float4* sA4 = (float4*)sA;
        for (int idx = tid; idx < nb * 32; idx += NT) sA4[idx] = xg[idx];
    }
    float whc[4][4], wf[4][4];
#pragma unroll
    for (int j = 0; j < 4; ++j)
#pragma unroll
        for (int i = 0; i < 4; ++i) { whc[j][i] = 0.f; wf[j][i] = 0.f; }
    for (int k0 = 0; k0 < 128; k0 += 16) {
        __syncthreads();
        const float4* Wg = (const float4*)Ww;
        for (int idx = tid; idx < 256 * 4; idx += NT) {
            int j2 = idx >> 2, kq = idx & 3;
            float4 v = Wg[j2 * 32 + (k0 >> 2) + kq];
            int kb = kq << 2;
            sW[(kb + 0) * 260 + j2] = v.x; sW[(kb + 1) * 260 + j2] = v.y;
            sW[(kb + 2) * 260 + j2] = v.z; sW[(kb + 3) * 260 + j2] = v.w;
        }
        __syncthreads();
#pragma unroll
        for (int kk = 0; kk < 16; kk += 4) {
            float4 a4[4];
#pragma unroll
            for (int i = 0; i < 4; ++i)
                a4[i] = ((const float4*)sA)[(i0 + i) * 32 + ((k0 + kk) >> 2)];
#pragma unroll
            for (int u = 0; u < 4; ++u) {
                int k = kk + u;
                float4 w0 = *((const float4*)&sW[k * 260 + j0]);
                float4 w1 = *((const float4*)&sW[k * 260 + 128 + j0]);
                const float* w0p = (const float*)&w0;
                const float* w1p = (const float*)&w1;
#pragma unroll
                for (int i = 0; i < 4; ++i) {
                    float av = ((const float*)&a4[i])[u];
#pragma unroll
                    for (int j = 0; j < 4; ++j) {
                        whc[j][i] = fmaf(w0p[j], av, whc[j][i]);
                        wf[j][i]  = fmaf(w1p[j], av, wf[j][i]);
                    }
                }
            }
        }
    }
#pragma unroll
    for (int j = 0; j < 4; ++j) {
        float bhc = Wb[j0 + j], bf = Wb[128 + j0 + j];
#pragma unroll
        for (int i = 0; i < 4; ++i) { whc[j][i] += bhc; wf[j][i] += bf; }
    }
    __syncthreads();
    {
        const float4* hg = (const float4*)(h + ((size_t)2 * s0 + 1) * 128);
        float4* sA4 = (float4*)sA;
        for (int idx = tid; idx < nb * 64; idx += NT) sA4[idx] = hg[idx];
    }
    float fv[4][4];
#pragma unroll
    for (int j = 0; j < 4; ++j)
#pragma unroll
        for (int i = 0; i < 4; ++i) fv[j][i] = 0.f;
    for (int k0 = 0; k0 < 256; k0 += 32) {
        __syncthreads();
        const float4* Ug = (const float4*)Uf;
        for (int idx = tid; idx < 128 * 8; idx += NT) {
            int j2 = idx >> 3, kq = idx & 7;
            float4 v = Ug[j2 * 64 + (k0 >> 2) + kq];
            int kb = kq << 2;
            sW[(kb + 0) * 132 + j2] = v.x; sW[(kb + 1) * 132 + j2] = v.y;
            sW[(kb + 2) * 132 + j2] = v.z; sW[(kb + 3) * 132 + j2] = v.w;
        }
        __syncthreads();
#pragma unroll
        for (int kk = 0; kk < 32; kk += 4) {
            float4 a4[4];
#pragma unroll
            for (int i = 0; i < 4; ++i)
                a4[i] = ((const float4*)sA)[(i0 + i) * 64 + ((k0 + kk) >> 2)];
#pragma unroll
            for (int u = 0; u < 4; ++u) {
                int k = kk + u;
                float4 w = *((const float4*)&sW[k * 132 + j0]);
                const float* wp = (const float*)&w;
#pragma unroll
                for (int i = 0; i < 4; ++i) {
                    float av = ((const float*)&a4[i])[u];
#pragma unroll
                    for (int j = 0; j < 4; ++j)
                        fv[j][i] = fmaf(wp[j], av, fv[j][i]);
                }
            }
        }
    }
#pragma unroll
    for (int j = 0; j < 4; ++j)
#pragma unroll
        for (int i = 0; i < 4; ++i)
            fv[j][i] = sigmoid_(fv[j][i] + wf[j][i]);
    __syncthreads();
    float hs[4][4];
#pragma unroll
    for (int i = 0; i < 4; ++i) {
        float4* row = (float4*)&sA[(i0 + i) * 256];
        float4 c0 = row[jq], c1 = row[32 + jq];
        hs[0][i] = c0.x + c1.x; hs[1][i] = c0.y + c1.y;
        hs[2][i] = c0.z + c1.z; hs[3][i] = c0.w + c1.w;
        c0.x *= fv[0][i]; c0.y *= fv[1][i]; c0.z *= fv[2][i]; c0.w *= fv[3][i];
        c1.x *= fv[0][i]; c1.y *= fv[1][i]; c1.z *= fv[2][i]; c1.w *= fv[3][i];
        row[jq] = c0; row[32 + jq] = c1;
    }
    float cv[4][4];
#pragma unroll
    for (int j = 0; j < 4; ++j)
#pragma unroll
        for (int i = 0; i < 4; ++i) cv[j][i] = 0.f;
    for (int k0 = 0; k0 < 256; k0 += 32) {
        __syncthreads();
        const float4* Ug = (const float4*)Uhc;
        for (int idx = tid; idx < 128 * 8; idx += NT) {
            int j2 = idx >> 3, kq = idx & 7;
            float4 v = Ug[j2 * 64 + (k0 >> 2) + kq];
            int kb = kq << 2;
            sW[(kb + 0) * 132 + j2] = v.x; sW[(kb + 1) * 132 + j2] = v.y;
            sW[(kb + 2) * 132 + j2] = v.z; sW[(kb + 3) * 132 + j2] = v.w;
        }
        __syncthreads();
#pragma unroll
        for (int kk = 0; kk < 32; kk += 4) {
            float4 a4[4];
#pragma unroll
            for (int i = 0; i < 4; ++i)
                a4[i] = ((const float4*)sA)[(i0 + i) * 64 + ((k0 + kk) >> 2)];
#pragma unroll
            for (int u = 0; u < 4; ++u) {
                int k = kk + u;
                float4 w = *((const float4*)&sW[k * 132 + j0]);
                const float* wp = (const float*)&w;
#pragma unroll
                for (int i = 0; i < 4; ++i) {
                    float av = ((const float*)&a4[i])[u];
#pragma unroll
                    for (int j = 0; j < 4; ++j)
                        cv[j][i] = fmaf(wp[j], av, cv[j][i]);
                }
            }
        }
    }
#pragma unroll
    for (int i = 0; i < 4; ++i) {
        if (i0 + i < nb) {
            float4 o; float* op = (float*)&o;
#pragma unroll
            for (int j = 0; j < 4; ++j) {
                float t = tanhf(cv[j][i] + whc[j][i]);
                op[j] = fv[j][i] * hs[j][i] + (1.0f - fv[j][i]) * t;
            }
            *(float4*)&h[((size_t)(s0 + i0 + i)) * 128 + j0] = o;
        }
    }
}

// =================== launcher ===================

extern "C" void kernel_launch(void* const* d_in, const int* in_sizes, int n_in,
                              void* d_out, int out_size, void* d_ws, size_t ws_size,
                              hipStream_t stream)
{
    (void)in_sizes; (void)n_in; (void)out_size;
    const float* x   = (const float*)d_in[0];
    const float* Ww  = (const float*)d_in[1];
    const float* Wb  = (const float*)d_in[2];
    const float* Uf  = (const float*)d_in[3];
    const float* Uhc = (const float*)d_in[4];
    float* h = (float*)d_out;
    const int depth = 18;

    if (ws_size >= WS_BYTES) {
        float* ws = (float*)d_ws;
        prep_pack<<<544, NT, 0, stream>>>(Ww, Uf, Uhc, ws);
        wx_mfma4<<<2048, 512, 0, stream>>>(x, ws, Wb, ws, h);
        for (int lvl = 16; lvl >= 12; --lvl)                     // big levels: A-in-reg MFMA
            lvl_reg<<<1 << (lvl - 6), 512, 0, stream>>>(ws, h, (1 << lvl) - 1);
        for (int lvl = 11; lvl >= 6; --lvl) {                    // small levels: fp32, low latency
            int start = (1 << lvl) - 1;
            int size  = 1 << lvl;
            level_kernel<<<(size + B_NB - 1) / B_NB, NT, 0, stream>>>(ws, h, start, size);
        }
        tail_kernel<<<1, NT, 0, stream>>>(ws, h);
    } else {
        {
            int lvl = depth - 1;
            int start = (1 << lvl) - 1, size = 1 << lvl;
            fb_leaf<<<(size + 31) / 32, NT, 0, stream>>>(x, Ww, Wb, h, start, size);
        }
        for (int lvl = depth - 2; lvl >= 0; --lvl) {
            int start = (1 << lvl) - 1, size = 1 << lvl;
            fb_internal<<<(size + 31) / 32, NT, 0, stream>>>(x, Ww, Wb, Uf, Uhc, h, start, size);
        }
    }
}